// Round 2
// baseline (453.388 us; speedup 1.0000x reference)
//
#include <hip/hip_runtime.h>

// IDWT (Haar, stride-2 transposed conv, grouped):
//   x: [B, 4C, H, W] f32, filters: [4,2,2] f32
//   out[b, c, 2h+p, 2w+q] = sum_s x[b, s*C+c, h, w] * f[s, p, q]
// B=16, 4C=256 (C=64), H=W=128 -> out [16, 64, 256, 256]
//
// Pure streaming kernel: in (268 MB) read once, out (268 MB) written once,
// zero temporal reuse. Out stream > LLC (256 MB) -> cached stores churn
// dirty LLC lines. This round: non-temporal loads/stores to bypass cache
// allocation on both streams. NOTE: __builtin_nontemporal_* requires a
// NATIVE vector type (ext_vector_type), not HIP's float4 class.

constexpr int B = 16;
constexpr int C = 64;
constexpr int H = 128;
constexpr int W = 128;
constexpr int W4 = W / 4;                 // 32 quads per row
constexpr long N_THREADS = (long)B * C * H * W4;   // 4,194,304 (= 16384 * 256 exactly)

typedef float f32x4 __attribute__((ext_vector_type(4)));

__device__ __forceinline__ f32x4 nt_load4(const float* p) {
    return __builtin_nontemporal_load(reinterpret_cast<const f32x4*>(p));
}
__device__ __forceinline__ void nt_store4(float* p, f32x4 v) {
    __builtin_nontemporal_store(v, reinterpret_cast<f32x4*>(p));
}

__global__ __launch_bounds__(256) void idwt_kernel(
    const float* __restrict__ x,
    const float* __restrict__ f,
    float* __restrict__ out)
{
    const int idx = blockIdx.x * 256 + threadIdx.x;   // grid divides exactly, no tail

    // idx -> (b, c, h, w4); all dims are powers of two
    const int w4 = idx & (W4 - 1);        // 5 bits
    const int h  = (idx >> 5) & (H - 1);  // 7 bits
    const int c  = (idx >> 12) & (C - 1); // 6 bits
    const int b  = idx >> 18;

    const long sStride = (long)C * H * W;                       // subband stride
    const long inBase  = (((long)b * 4 * C + c) * H + h) * W + (long)w4 * 4;

    const f32x4 va = nt_load4(x + inBase);
    const f32x4 vb = nt_load4(x + inBase + sStride);
    const f32x4 vc = nt_load4(x + inBase + 2 * sStride);
    const f32x4 vd = nt_load4(x + inBase + 3 * sStride);

    // filters[s][p][q], flat: f[s*4 + p*2 + q] -- uniform addresses -> s_load
    const float f00 = f[0],  f01 = f[1],  f02 = f[2],  f03 = f[3];
    const float f10 = f[4],  f11 = f[5],  f12 = f[6],  f13 = f[7];
    const float f20 = f[8],  f21 = f[9],  f22 = f[10], f23 = f[11];
    const float f30 = f[12], f31 = f[13], f32 = f[14], f33 = f[15];

    float r0[8], r1[8];
    #pragma unroll
    for (int j = 0; j < 4; ++j) {
        const float a = va[j], bb = vb[j], cc = vc[j], dd = vd[j];
        r0[2*j]     = a*f00 + bb*f10 + cc*f20 + dd*f30;   // p=0,q=0
        r0[2*j + 1] = a*f01 + bb*f11 + cc*f21 + dd*f31;   // p=0,q=1
        r1[2*j]     = a*f02 + bb*f12 + cc*f22 + dd*f32;   // p=1,q=0
        r1[2*j + 1] = a*f03 + bb*f13 + cc*f23 + dd*f33;   // p=1,q=1
    }

    // output: rows 2h and 2h+1, cols 8*w4 .. 8*w4+7 (contiguous)
    const long outBase = (((long)b * C + c) * (2 * H) + (long)2 * h) * (2 * W)
                         + (long)w4 * 8;
    nt_store4(out + outBase,             f32x4{r0[0], r0[1], r0[2], r0[3]});
    nt_store4(out + outBase + 4,         f32x4{r0[4], r0[5], r0[6], r0[7]});
    nt_store4(out + outBase + 2 * W,     f32x4{r1[0], r1[1], r1[2], r1[3]});
    nt_store4(out + outBase + 2 * W + 4, f32x4{r1[4], r1[5], r1[6], r1[7]});
}

extern "C" void kernel_launch(void* const* d_in, const int* in_sizes, int n_in,
                              void* d_out, int out_size, void* d_ws, size_t ws_size,
                              hipStream_t stream) {
    const float* x = (const float*)d_in[0];
    const float* f = (const float*)d_in[1];
    float* out = (float*)d_out;

    const int threads = 256;
    const int blocks = (int)(N_THREADS / threads);  // 16384, exact
    idwt_kernel<<<blocks, threads, 0, stream>>>(x, f, out);
}

// Round 3
// 426.055 us; speedup vs baseline: 1.0642x; 1.0642x over previous
//
#include <hip/hip_runtime.h>

// IDWT (Haar, stride-2 transposed conv, grouped):
//   x: [B, 4C, H, W] f32, filters: [4,2,2] f32
//   out[b, c, 2h+p, 2w+q] = sum_s x[b, s*C+c, h, w] * f[s, p, q]
// B=16, 4C=256 (C=64), H=W=128 -> out [16, 64, 256, 256]
//
// Round 2 post-mortem: nt stores regressed (453 vs 430) because stores were
// HALF-DENSE per instruction (16B written every 32B; the +4 partner instr
// filled the gaps). Cached L2 merged them; nt exposed partial-line RMW.
// Round 3: revert nt; restructure one-thread-per-input-PAIR so every
// load instruction (64 x 8B = 512B) and every store instruction
// (64 x 16B = 1KB = one full output row) is fully dense. No shuffles needed.

constexpr int B = 16;
constexpr int C = 64;
constexpr int H = 128;
constexpr int W = 128;
constexpr int W2 = W / 2;                 // 64 input pixel-pairs per row
constexpr long N_THREADS = (long)B * C * H * W2;   // 8,388,608 = 32768 * 256 exactly

typedef float f32x2 __attribute__((ext_vector_type(2)));
typedef float f32x4 __attribute__((ext_vector_type(4)));

__global__ __launch_bounds__(256) void idwt_kernel(
    const float* __restrict__ x,
    const float* __restrict__ f,
    float* __restrict__ out)
{
    const int idx = blockIdx.x * 256 + threadIdx.x;   // grid divides exactly, no tail

    // idx -> (b, c, h, t); all dims are powers of two.
    // t = input pixel-pair index in the row. One full wave (64 lanes) = one
    // complete input row per subband, and one complete output row per store.
    const int t = idx & (W2 - 1);          // 6 bits
    const int h = (idx >> 6) & (H - 1);    // 7 bits
    const int c = (idx >> 13) & (C - 1);   // 6 bits
    const int b = idx >> 19;

    const long sStride = (long)C * H * W;                       // subband stride
    const long inBase  = (((long)b * 4 * C + c) * H + h) * W + (long)t * 2;

    const f32x2 va = *reinterpret_cast<const f32x2*>(x + inBase);
    const f32x2 vb = *reinterpret_cast<const f32x2*>(x + inBase + sStride);
    const f32x2 vc = *reinterpret_cast<const f32x2*>(x + inBase + 2 * sStride);
    const f32x2 vd = *reinterpret_cast<const f32x2*>(x + inBase + 3 * sStride);

    // filters[s][p][q], flat: f[s*4 + p*2 + q] -- uniform addresses -> s_load
    const float f00 = f[0],  f01 = f[1],  f02 = f[2],  f03 = f[3];
    const float f10 = f[4],  f11 = f[5],  f12 = f[6],  f13 = f[7];
    const float f20 = f[8],  f21 = f[9],  f22 = f[10], f23 = f[11];
    const float f30 = f[12], f31 = f[13], f32 = f[14], f33 = f[15];

    float r0[4], r1[4];
    #pragma unroll
    for (int j = 0; j < 2; ++j) {
        const float a = va[j], bb = vb[j], cc = vc[j], dd = vd[j];
        r0[2*j]     = a*f00 + bb*f10 + cc*f20 + dd*f30;   // p=0,q=0
        r0[2*j + 1] = a*f01 + bb*f11 + cc*f21 + dd*f31;   // p=0,q=1
        r1[2*j]     = a*f02 + bb*f12 + cc*f22 + dd*f32;   // p=1,q=0
        r1[2*j + 1] = a*f03 + bb*f13 + cc*f23 + dd*f33;   // p=1,q=1
    }

    // output: rows 2h and 2h+1, cols 4t..4t+3 (one dense float4 per row;
    // a wave's 64 lanes cover the full 1 KB output row contiguously)
    const long outBase = (((long)b * C + c) * (2 * H) + (long)2 * h) * (2 * W)
                         + (long)t * 4;
    *reinterpret_cast<f32x4*>(out + outBase)         = f32x4{r0[0], r0[1], r0[2], r0[3]};
    *reinterpret_cast<f32x4*>(out + outBase + 2 * W) = f32x4{r1[0], r1[1], r1[2], r1[3]};
}

extern "C" void kernel_launch(void* const* d_in, const int* in_sizes, int n_in,
                              void* d_out, int out_size, void* d_ws, size_t ws_size,
                              hipStream_t stream) {
    const float* x = (const float*)d_in[0];
    const float* f = (const float*)d_in[1];
    float* out = (float*)d_out;

    const int threads = 256;
    const int blocks = (int)(N_THREADS / threads);  // 32768, exact
    idwt_kernel<<<blocks, threads, 0, stream>>>(x, f, out);
}